// Round 6
// baseline (388.383 us; speedup 1.0000x reference)
//
#include <hip/hip_runtime.h>

#define NT      250000
#define NN      20000
#define RP      8
#define EMB     64
#define NCLS    16
#define NRELS   64
#define NQUAD   62500     // NT/4 (rows per wave = 4)
#define COLB    547       // ceil(NN*7/256)
#define REDB    64
#define SEGMAX  140000    // max written segment id + 1 (19999*7 = 139993)

// ---------------- A: wave-cooperative GEMV + softmax ----------------
// 4 rows/wave, 16 lanes/row. One dwordx4/lane = 1KB contiguous rm per wave.
// W fragments register-resident. Butterfly allreduce over 16 lanes.
__global__ __launch_bounds__(256) void k_gemv(
    const float* __restrict__ rm,
    const float* __restrict__ W1, const float* __restrict__ b1,
    const float* __restrict__ W2, const float* __restrict__ b2,
    float* __restrict__ l1, float* __restrict__ l2)    // [NT][8] each
{
    int wave = (int)((blockIdx.x * blockDim.x + threadIdx.x) >> 6);
    int lane = threadIdx.x & 63;
    int c    = lane & 15;                 // k-chunk: covers k = 4c..4c+3
    float w1f[4][8], w2f[4][8];
    const float4* W14 = reinterpret_cast<const float4*>(W1);
    const float4* W24 = reinterpret_cast<const float4*>(W2);
#pragma unroll
    for (int j = 0; j < 4; ++j) {
        int k = 4 * c + j;
        float4 A = W14[k * 2], B = W14[k * 2 + 1];
        w1f[j][0]=A.x; w1f[j][1]=A.y; w1f[j][2]=A.z; w1f[j][3]=A.w;
        w1f[j][4]=B.x; w1f[j][5]=B.y; w1f[j][6]=B.z; w1f[j][7]=B.w;
        float4 C = W24[k * 2], D = W24[k * 2 + 1];
        w2f[j][0]=C.x; w2f[j][1]=C.y; w2f[j][2]=C.z; w2f[j][3]=C.w;
        w2f[j][4]=D.x; w2f[j][5]=D.y; w2f[j][6]=D.z; w2f[j][7]=D.w;
    }
    if (wave >= NQUAD) return;
    float4 rv = reinterpret_cast<const float4*>(rm)[(size_t)wave * 64 + lane];
    float xs[4] = {rv.x, rv.y, rv.z, rv.w};
    float a1[8], a2[8];
#pragma unroll
    for (int r = 0; r < 8; ++r) { a1[r] = 0.f; a2[r] = 0.f; }
#pragma unroll
    for (int j = 0; j < 4; ++j) {
        float x = xs[j];
#pragma unroll
        for (int r = 0; r < 8; ++r) {
            a1[r] = fmaf(x, w1f[j][r], a1[r]);
            a2[r] = fmaf(x, w2f[j][r], a2[r]);
        }
    }
#pragma unroll
    for (int m = 1; m <= 8; m <<= 1) {
#pragma unroll
        for (int r = 0; r < 8; ++r) {
            a1[r] += __shfl_xor(a1[r], m, 64);
            a2[r] += __shfl_xor(a2[r], m, 64);
        }
    }
#pragma unroll
    for (int r = 0; r < 8; ++r) { a1[r] += b1[r]; a2[r] += b2[r]; }
    float mx = a2[0];
#pragma unroll
    for (int r = 1; r < 8; ++r) mx = fmaxf(mx, a2[r]);
    float sm = 0.f;
#pragma unroll
    for (int r = 0; r < 8; ++r) { a2[r] = __expf(a2[r] - mx); sm += a2[r]; }
    float inv = 1.0f / sm;
#pragma unroll
    for (int r = 0; r < 8; ++r) a2[r] *= inv;
    int o = lane & 15;
    int p = wave * 4 + (lane >> 4);
    float val = a1[0];
#pragma unroll
    for (int i = 1; i < 8; ++i) val = (o == i) ? a1[i] : val;
#pragma unroll
    for (int i = 0; i < 8; ++i) val = (o == 8 + i) ? a2[i] : val;
    float* dst = (o < 8) ? (l1 + (size_t)p * 8 + o) : (l2 + (size_t)p * 8 + (o - 8));
    *dst = val;
}

// ---------------- CSR offsets (hrow sorted by np.unique) ----------------
__global__ __launch_bounds__(256) void k_rowptr(
    const int* __restrict__ hrow, int* __restrict__ rowptr)
{
    int i = blockIdx.x * blockDim.x + threadIdx.x;
    if (i > NN) return;
    int lo = 0, hi = NT;
    while (lo < hi) { int mid = (lo + hi) >> 1; if (hrow[mid] < i) lo = mid + 1; else hi = mid; }
    rowptr[i] = lo;
}

// ---------------- CSC build ----------------
__global__ __launch_bounds__(256) void k_hist(
    const int* __restrict__ vcol, int* __restrict__ cnt)
{
    int p = blockIdx.x * blockDim.x + threadIdx.x;
    if (p < NT) atomicAdd(&cnt[vcol[p]], 1);
}

__global__ __launch_bounds__(1024) void k_scan(
    const int* __restrict__ cnt, int* __restrict__ cstart, int* __restrict__ cnt2)
{
    __shared__ int part[1024];
    int t = threadIdx.x;
    int base = t * 20;
    int local[20];
    int s = 0;
#pragma unroll
    for (int i = 0; i < 20; ++i) {
        int idx = base + i;
        int c = (idx < NN) ? cnt[idx] : 0;
        local[i] = s;
        s += c;
    }
    part[t] = s;
    __syncthreads();
    for (int off = 1; off < 1024; off <<= 1) {
        int v = (t >= off) ? part[t - off] : 0;
        __syncthreads();
        part[t] += v;
        __syncthreads();
    }
    int ebase = t ? part[t - 1] : 0;
#pragma unroll
    for (int i = 0; i < 20; ++i) {
        int idx = base + i;
        if (idx < NN) { cstart[idx] = ebase + local[i]; cnt2[idx] = ebase + local[i]; }
    }
    if (t == 1023) cstart[NN] = part[1023];
}

__global__ __launch_bounds__(256) void k_pos(
    const int* __restrict__ vcol, int* __restrict__ cnt2, int* __restrict__ cscidx)
{
    int p = blockIdx.x * blockDim.x + threadIdx.x;
    if (p >= NT) return;
    int o = vcol[p];
    int slot = atomicAdd(&cnt2[o], 1);
    cscidx[slot] = p;
}

// ---------------- colsum via CSC gather-reduce (+ colsum[0] reducers) ----------------
__global__ __launch_bounds__(256) void k_colsum(
    const float* __restrict__ l1, const int* __restrict__ cstart,
    const int* __restrict__ cscidx, float* __restrict__ colsum)
{
    int bid = blockIdx.x;
    if (bid < COLB) {
        int tid = bid * 256 + threadIdx.x;
        if (tid < NN * 7) {
            int o = tid / 7;
            int r = tid - o * 7 + 1;
            int qb = cstart[o], qe = cstart[o + 1];
            float s = 0.f;
            for (int q = qb; q < qe; ++q)
                s += l1[(size_t)cscidx[q] * 8 + r];
            atomicAdd(&colsum[o * r], s);
        }
    } else {
        int b2 = bid - COLB;
        float s = 0.f;
        for (int i = b2 * 256 + threadIdx.x; i < NT; i += REDB * 256) s += l1[(size_t)i * 8];
        __shared__ float red[256];
        red[threadIdx.x] = s;
        __syncthreads();
        for (int off = 128; off > 0; off >>= 1) {
            if (threadIdx.x < off) red[threadIdx.x] += red[threadIdx.x + off];
            __syncthreads();
        }
        if (threadIdx.x == 0) atomicAdd(&colsum[0], red[0]);
    }
}

// ---------------- invert colsum in place (empty segs -> inf, never read) ----------------
__global__ __launch_bounds__(256) void k_inv(float* __restrict__ cs)
{
    int i = blockIdx.x * blockDim.x + threadIdx.x;
    if (i < RP * NN) cs[i] = 1.0f / cs[i];
}

// ---------------- C: one wave per node s; multiply by inverse colsum ----------------
__global__ __launch_bounds__(256) void k_h(
    const float* __restrict__ l1, const float* __restrict__ ics,
    const int* __restrict__ rowptr, const int* __restrict__ vcol,
    const float* __restrict__ w1, const float* __restrict__ bias1,
    float* __restrict__ h)
{
    int wave = (int)((blockIdx.x * blockDim.x + threadIdx.x) >> 6);
    int lane = threadIdx.x & 63;
    if (wave >= NN) return;
    int pb = rowptr[wave], pe = rowptr[wave + 1];
    float ics0 = ics[0];
    float acc = 0.f, c0 = 0.f;
    for (int p = pb; p < pe; ++p) {
        int o = vcol[p];
        const float* lp = l1 + (size_t)p * 8;
        c0 += lp[0];
#pragma unroll
        for (int r = 1; r < 8; ++r) {
            int seg = o * r;
            acc = fmaf(lp[r] * ics[seg], w1[(size_t)seg * EMB + lane], acc);
        }
    }
    acc = fmaf(c0 * ics0, w1[lane], acc);
    h[(size_t)wave * EMB + lane] = fmaxf(acc + bias1[lane], 0.f);
}

// ---------------- D: one wave per node s; register-resident 8x64 block ----------------
__global__ __launch_bounds__(256) void k_h2(
    const float* __restrict__ l2, const int* __restrict__ rowptr,
    const int* __restrict__ vcol, const float* __restrict__ h,
    float* __restrict__ h2raw, float* __restrict__ rowsum,
    float* __restrict__ Abuf0, float* __restrict__ rs0part)
{
    int wave = (int)((blockIdx.x * blockDim.x + threadIdx.x) >> 6);
    int lane = threadIdx.x & 63;
    if (wave >= NN) return;
    int s = wave;
    int pb = rowptr[s], pe = rowptr[s + 1];
    float acc[RP], rs[RP];
#pragma unroll
    for (int r = 0; r < RP; ++r) { acc[r] = 0.f; rs[r] = 0.f; }
    for (int p = pb; p < pe; ++p) {
        int o = vcol[p];
        float hv = h[(size_t)o * EMB + lane];
        const float* lp = l2 + (size_t)p * 8;
#pragma unroll
        for (int r = 0; r < RP; ++r) {
            float lv = lp[r];
            acc[r] = fmaf(lv, hv, acc[r]);
            rs[r] += lv;
        }
    }
    if (s == 0) {
        float a0 = 0.f, r0 = 0.f;
#pragma unroll
        for (int r = 0; r < RP; ++r) { a0 += acc[r]; r0 += rs[r]; }
        Abuf0[lane] = a0;
        if (lane == 0) rs0part[0] = r0;
    } else {
        Abuf0[(size_t)s * EMB + lane] = acc[0];
        if (lane == 0) rs0part[s] = rs[0];
#pragma unroll
        for (int r = 1; r < RP; ++r) {
            int seg = s * r;
            atomicAdd(&h2raw[(size_t)seg * EMB + lane], acc[r]);
            if (lane == 0) atomicAdd(&rowsum[seg], rs[r]);
        }
    }
}

// ---------------- reduce seg-0 partials ----------------
__global__ __launch_bounds__(256) void k_red0(
    const float* __restrict__ Abuf0, const float* __restrict__ rs0part,
    float* __restrict__ h2raw, float* __restrict__ rowsum)
{
    __shared__ float red[256];
    if (blockIdx.x < 64) {
        int lane = threadIdx.x & 63, w = threadIdx.x >> 6;
        float sum = 0.f;
        for (int ss = blockIdx.x + 64 * w; ss < NN; ss += 256)
            sum += Abuf0[(size_t)ss * EMB + lane];
        red[threadIdx.x] = sum;
        __syncthreads();
        if (threadIdx.x < 64) {
            float v = red[threadIdx.x] + red[threadIdx.x + 64] +
                      red[threadIdx.x + 128] + red[threadIdx.x + 192];
            atomicAdd(&h2raw[threadIdx.x], v);
        }
    } else {
        float sum = 0.f;
        for (int ssp = (int)threadIdx.x; ssp < NN; ssp += 256) sum += rs0part[ssp];
        red[threadIdx.x] = sum;
        __syncthreads();
        for (int off = 128; off > 0; off >>= 1) {
            if (threadIdx.x < off) red[threadIdx.x] += red[threadIdx.x + off];
            __syncthreads();
        }
        if (threadIdx.x == 0) atomicAdd(&rowsum[0], red[0]);
    }
}

// ---------------- E: fused /rowsum + einsum + bias2 ----------------
// ONLY the r=7 plane (rows 140000..159999, never written) is skipped.
// r=0 plane reads segments 0..19999 which ARE populated -> full loop r=0..6.
__global__ __launch_bounds__(1024) void k_logits(
    const float* __restrict__ h2raw, const float* __restrict__ rowsum,
    const float* __restrict__ w2, const float* __restrict__ bias2,
    float* __restrict__ out)
{
    __shared__ float w2s[RP * EMB * NCLS];   // 32 KB
    for (int i = threadIdx.x; i < RP * EMB * NCLS; i += 1024) w2s[i] = w2[i];
    __syncthreads();
    int wv = threadIdx.x >> 6, lane = threadIdx.x & 63;
    int n = blockIdx.x * 16 + wv;            // grid=1250 -> n < 20000 exactly
    int c = lane & 15, es = lane >> 4;
    float acc = 0.f;
#pragma unroll
    for (int r = 0; r <= 6; ++r) {
        size_t k = (size_t)r * NN + n;
        float hv = h2raw[k * EMB + lane] / fmaxf(rowsum[k], 1e-6f);
#pragma unroll
        for (int eo = 0; eo < 16; ++eo) {
            float he = __shfl(hv, es * 16 + eo, 64);
            acc = fmaf(he, w2s[(r * EMB + es * 16 + eo) * NCLS + c], acc);
        }
    }
    acc += __shfl_xor(acc, 16, 64);
    acc += __shfl_xor(acc, 32, 64);
    if (lane < 16) out[(size_t)n * NCLS + lane] = acc + bias2[lane];
}

extern "C" void kernel_launch(void* const* d_in, const int* in_sizes, int n_in,
                              void* d_out, int out_size, void* d_ws, size_t ws_size,
                              hipStream_t stream)
{
    const float* rm    = (const float*)d_in[0];
    const int*   hrow  = (const int*)d_in[1];   // sorted source nodes
    const int*   vcol  = (const int*)d_in[4];   // object nodes
    const float* W1    = (const float*)d_in[5];
    const float* b1    = (const float*)d_in[6];
    const float* W2    = (const float*)d_in[7];
    const float* b2    = (const float*)d_in[8];
    const float* w1    = (const float*)d_in[9];
    const float* w2    = (const float*)d_in[10];
    const float* bias1 = (const float*)d_in[11];
    const float* bias2 = (const float*)d_in[12];
    float* out = (float*)d_out;

    float* ws      = (float*)d_ws;
    float* l1      = ws;                    // 2,000,000  [NT][8]
    float* l2      = ws + 2000000;          // 2,000,000  [NT][8]
    float* colsum  = ws + 4000000;          // 160,000 (becomes inverse in-place)
    float* rowsum  = ws + 4160000;          // 160,000
    float* h       = ws + 4320000;          // 1,280,000 (written by k_h)
    float* h2raw   = ws + 5600000;          // 10,240,000
    int*   rowptr  = (int*)(ws + 15840000); // 20,001 ints
    // CSC scratch aliases the h region (dead before k_h writes h)
    int* cnt    = (int*)(ws + 4320000);     // 20,000
    int* cstart = cnt + 20000;              // 20,001
    int* cnt2   = cstart + 20001;           // 20,000
    int* cscidx = cnt2 + 20000;             // 250,000
    // Abuf0/rs0part overlay l1 (dead after k_h)
    float* Abuf0   = ws;                    // 1,280,000
    float* rs0part = ws + 1280000;          // 20,000

    hipMemsetAsync(colsum, 0, (size_t)320000 * sizeof(float), stream);   // colsum+rowsum
    hipMemsetAsync(h2raw, 0, (size_t)SEGMAX * EMB * sizeof(float), stream); // all read/written rows
    hipMemsetAsync(cnt, 0, (size_t)20000 * sizeof(int), stream);

    k_rowptr<<<(NN + 256) / 256, 256, 0, stream>>>(hrow, rowptr);
    k_hist  <<<(NT + 255) / 256, 256, 0, stream>>>(vcol, cnt);
    k_scan  <<<1, 1024, 0, stream>>>(cnt, cstart, cnt2);
    k_pos   <<<(NT + 255) / 256, 256, 0, stream>>>(vcol, cnt2, cscidx);
    k_gemv  <<<NQUAD * 64 / 256, 256, 0, stream>>>(rm, W1, b1, W2, b2, l1, l2);
    k_colsum<<<COLB + REDB, 256, 0, stream>>>(l1, cstart, cscidx, colsum);
    k_inv   <<<(RP * NN + 255) / 256, 256, 0, stream>>>(colsum);
    k_h     <<<(NN * 64) / 256, 256, 0, stream>>>(l1, colsum, rowptr, vcol, w1, bias1, h);
    k_h2    <<<(NN * 64) / 256, 256, 0, stream>>>(l2, rowptr, vcol, h, h2raw, rowsum, Abuf0, rs0part);
    k_red0  <<<65, 256, 0, stream>>>(Abuf0, rs0part, h2raw, rowsum);
    k_logits<<<NN / 16, 1024, 0, stream>>>(h2raw, rowsum, w2, bias2, out);
}

// Round 7
// 300.684 us; speedup vs baseline: 1.2917x; 1.2917x over previous
//
#include <hip/hip_runtime.h>

#define NT      250000
#define NN      20000
#define RP      8
#define EMB     64
#define NCLS    16
#define NRELS   64
#define COLB    547       // ceil(NN*7/256)
#define REDB    64
#define SEGMAX  140000    // max written segment id + 1 (19999*7 = 139993)

// ---------------- A: LDS-row-tiled per-thread GEMV + softmax ----------------
// 256 rows/block, 4 k-chunks of 16. tile[256][20]: 20-pad keeps float4 aligned
// and spreads banks uniformly for both the staged write and the row read.
// W1/W2 read with thread-uniform indices -> scalar loads (SGPR broadcast).
__global__ __launch_bounds__(256) void k_gemv(
    const float* __restrict__ rm,
    const float* __restrict__ W1, const float* __restrict__ b1,
    const float* __restrict__ W2, const float* __restrict__ b2,
    float* __restrict__ l1, float* __restrict__ l2)    // [NT][8] each
{
    __shared__ float tile[256 * 20];
    int t = threadIdx.x;
    int base = blockIdx.x * 256;
    float a1[8], a2[8];
#pragma unroll
    for (int r = 0; r < 8; ++r) { a1[r] = b1[r]; a2[r] = b2[r]; }

#pragma unroll 1
    for (int kc = 0; kc < 4; ++kc) {
        __syncthreads();               // protect previous chunk before overwrite
#pragma unroll
        for (int q = 0; q < 4; ++q) {
            int i = q * 256 + t;
            int pl = i >> 2, j4 = i & 3;
            int p = base + pl;
            float4 v = make_float4(0.f, 0.f, 0.f, 0.f);
            if (p < NT) v = reinterpret_cast<const float4*>(rm)[(size_t)p * 16 + kc * 4 + j4];
            *reinterpret_cast<float4*>(&tile[pl * 20 + j4 * 4]) = v;
        }
        __syncthreads();
        // row chunk -> registers (4 x ds_read_b128, bank-uniform)
        float xr[16];
#pragma unroll
        for (int j4 = 0; j4 < 4; ++j4) {
            float4 v = *reinterpret_cast<const float4*>(&tile[t * 20 + j4 * 4]);
            xr[j4 * 4 + 0] = v.x; xr[j4 * 4 + 1] = v.y;
            xr[j4 * 4 + 2] = v.z; xr[j4 * 4 + 3] = v.w;
        }
#pragma unroll
        for (int kk = 0; kk < 16; ++kk) {
            float x = xr[kk];
            int k = kc * 16 + kk;                 // uniform -> s_load
#pragma unroll
            for (int r = 0; r < 8; ++r) {
                a1[r] = fmaf(x, W1[k * 8 + r], a1[r]);
                a2[r] = fmaf(x, W2[k * 8 + r], a2[r]);
            }
        }
    }
    int p = base + t;
    if (p >= NT) return;
    // softmax over a2 (thread-local, no shuffles)
    float mx = a2[0];
#pragma unroll
    for (int r = 1; r < 8; ++r) mx = fmaxf(mx, a2[r]);
    float sm = 0.f;
#pragma unroll
    for (int r = 0; r < 8; ++r) { a2[r] = __expf(a2[r] - mx); sm += a2[r]; }
    float inv = 1.0f / sm;
#pragma unroll
    for (int r = 0; r < 8; ++r) a2[r] *= inv;
    float4* o1 = reinterpret_cast<float4*>(l1 + (size_t)p * 8);
    float4* o2 = reinterpret_cast<float4*>(l2 + (size_t)p * 8);
    o1[0] = make_float4(a1[0], a1[1], a1[2], a1[3]);
    o1[1] = make_float4(a1[4], a1[5], a1[6], a1[7]);
    o2[0] = make_float4(a2[0], a2[1], a2[2], a2[3]);
    o2[1] = make_float4(a2[4], a2[5], a2[6], a2[7]);
}

// ---------------- CSR offsets (hrow sorted by np.unique) ----------------
__global__ __launch_bounds__(256) void k_rowptr(
    const int* __restrict__ hrow, int* __restrict__ rowptr)
{
    int i = blockIdx.x * blockDim.x + threadIdx.x;
    if (i > NN) return;
    int lo = 0, hi = NT;
    while (lo < hi) { int mid = (lo + hi) >> 1; if (hrow[mid] < i) lo = mid + 1; else hi = mid; }
    rowptr[i] = lo;
}

// ---------------- CSC build ----------------
__global__ __launch_bounds__(256) void k_hist(
    const int* __restrict__ vcol, int* __restrict__ cnt)
{
    int p = blockIdx.x * blockDim.x + threadIdx.x;
    if (p < NT) atomicAdd(&cnt[vcol[p]], 1);
}

__global__ __launch_bounds__(1024) void k_scan(
    const int* __restrict__ cnt, int* __restrict__ cstart, int* __restrict__ cnt2)
{
    __shared__ int part[1024];
    int t = threadIdx.x;
    int base = t * 20;
    int local[20];
    int s = 0;
#pragma unroll
    for (int i = 0; i < 20; ++i) {
        int idx = base + i;
        int c = (idx < NN) ? cnt[idx] : 0;
        local[i] = s;
        s += c;
    }
    part[t] = s;
    __syncthreads();
    for (int off = 1; off < 1024; off <<= 1) {
        int v = (t >= off) ? part[t - off] : 0;
        __syncthreads();
        part[t] += v;
        __syncthreads();
    }
    int ebase = t ? part[t - 1] : 0;
#pragma unroll
    for (int i = 0; i < 20; ++i) {
        int idx = base + i;
        if (idx < NN) { cstart[idx] = ebase + local[i]; cnt2[idx] = ebase + local[i]; }
    }
    if (t == 1023) cstart[NN] = part[1023];
}

__global__ __launch_bounds__(256) void k_pos(
    const int* __restrict__ vcol, int* __restrict__ cnt2, int* __restrict__ cscidx)
{
    int p = blockIdx.x * blockDim.x + threadIdx.x;
    if (p >= NT) return;
    int o = vcol[p];
    int slot = atomicAdd(&cnt2[o], 1);
    cscidx[slot] = p;
}

// ---------------- colsum via CSC gather-reduce (+ colsum[0] reducers) ----------------
__global__ __launch_bounds__(256) void k_colsum(
    const float* __restrict__ l1, const int* __restrict__ cstart,
    const int* __restrict__ cscidx, float* __restrict__ colsum)
{
    int bid = blockIdx.x;
    if (bid < COLB) {
        int tid = bid * 256 + threadIdx.x;
        if (tid < NN * 7) {
            int o = tid / 7;
            int r = tid - o * 7 + 1;
            int qb = cstart[o], qe = cstart[o + 1];
            float s = 0.f;
            for (int q = qb; q < qe; ++q)
                s += l1[(size_t)cscidx[q] * 8 + r];
            atomicAdd(&colsum[o * r], s);
        }
    } else {
        int b2 = bid - COLB;
        float s = 0.f;
        for (int i = b2 * 256 + threadIdx.x; i < NT; i += REDB * 256) s += l1[(size_t)i * 8];
        __shared__ float red[256];
        red[threadIdx.x] = s;
        __syncthreads();
        for (int off = 128; off > 0; off >>= 1) {
            if (threadIdx.x < off) red[threadIdx.x] += red[threadIdx.x + off];
            __syncthreads();
        }
        if (threadIdx.x == 0) atomicAdd(&colsum[0], red[0]);
    }
}

// ---------------- invert colsum in place (empty segs -> inf, never read) ----------------
__global__ __launch_bounds__(256) void k_inv(float* __restrict__ cs)
{
    int i = blockIdx.x * blockDim.x + threadIdx.x;
    if (i < RP * NN) cs[i] = 1.0f / cs[i];
}

// ---------------- C: one wave per node s; multiply by inverse colsum ----------------
__global__ __launch_bounds__(256) void k_h(
    const float* __restrict__ l1, const float* __restrict__ ics,
    const int* __restrict__ rowptr, const int* __restrict__ vcol,
    const float* __restrict__ w1, const float* __restrict__ bias1,
    float* __restrict__ h)
{
    int wave = (int)((blockIdx.x * blockDim.x + threadIdx.x) >> 6);
    int lane = threadIdx.x & 63;
    if (wave >= NN) return;
    int pb = rowptr[wave], pe = rowptr[wave + 1];
    float ics0 = ics[0];
    float acc = 0.f, c0 = 0.f;
    for (int p = pb; p < pe; ++p) {
        int o = vcol[p];
        const float* lp = l1 + (size_t)p * 8;
        c0 += lp[0];
#pragma unroll
        for (int r = 1; r < 8; ++r) {
            int seg = o * r;
            acc = fmaf(lp[r] * ics[seg], w1[(size_t)seg * EMB + lane], acc);
        }
    }
    acc = fmaf(c0 * ics0, w1[lane], acc);
    h[(size_t)wave * EMB + lane] = fmaxf(acc + bias1[lane], 0.f);
}

// ---------------- D: one wave per node s; register-resident 8x64 block ----------------
__global__ __launch_bounds__(256) void k_h2(
    const float* __restrict__ l2, const int* __restrict__ rowptr,
    const int* __restrict__ vcol, const float* __restrict__ h,
    float* __restrict__ h2raw, float* __restrict__ rowsum,
    float* __restrict__ Abuf0, float* __restrict__ rs0part)
{
    int wave = (int)((blockIdx.x * blockDim.x + threadIdx.x) >> 6);
    int lane = threadIdx.x & 63;
    if (wave >= NN) return;
    int s = wave;
    int pb = rowptr[s], pe = rowptr[s + 1];
    float acc[RP], rs[RP];
#pragma unroll
    for (int r = 0; r < RP; ++r) { acc[r] = 0.f; rs[r] = 0.f; }
    for (int p = pb; p < pe; ++p) {
        int o = vcol[p];
        float hv = h[(size_t)o * EMB + lane];
        const float* lp = l2 + (size_t)p * 8;
#pragma unroll
        for (int r = 0; r < RP; ++r) {
            float lv = lp[r];
            acc[r] = fmaf(lv, hv, acc[r]);
            rs[r] += lv;
        }
    }
    if (s == 0) {
        float a0 = 0.f, r0 = 0.f;
#pragma unroll
        for (int r = 0; r < RP; ++r) { a0 += acc[r]; r0 += rs[r]; }
        Abuf0[lane] = a0;
        if (lane == 0) rs0part[0] = r0;
    } else {
        Abuf0[(size_t)s * EMB + lane] = acc[0];
        if (lane == 0) rs0part[s] = rs[0];
#pragma unroll
        for (int r = 1; r < RP; ++r) {
            int seg = s * r;
            atomicAdd(&h2raw[(size_t)seg * EMB + lane], acc[r]);
            if (lane == 0) atomicAdd(&rowsum[seg], rs[r]);
        }
    }
}

// ---------------- reduce seg-0 partials ----------------
__global__ __launch_bounds__(256) void k_red0(
    const float* __restrict__ Abuf0, const float* __restrict__ rs0part,
    float* __restrict__ h2raw, float* __restrict__ rowsum)
{
    __shared__ float red[256];
    if (blockIdx.x < 64) {
        int lane = threadIdx.x & 63, w = threadIdx.x >> 6;
        float sum = 0.f;
        for (int ss = blockIdx.x + 64 * w; ss < NN; ss += 256)
            sum += Abuf0[(size_t)ss * EMB + lane];
        red[threadIdx.x] = sum;
        __syncthreads();
        if (threadIdx.x < 64) {
            float v = red[threadIdx.x] + red[threadIdx.x + 64] +
                      red[threadIdx.x + 128] + red[threadIdx.x + 192];
            atomicAdd(&h2raw[threadIdx.x], v);
        }
    } else {
        float sum = 0.f;
        for (int ssp = (int)threadIdx.x; ssp < NN; ssp += 256) sum += rs0part[ssp];
        red[threadIdx.x] = sum;
        __syncthreads();
        for (int off = 128; off > 0; off >>= 1) {
            if (threadIdx.x < off) red[threadIdx.x] += red[threadIdx.x + off];
            __syncthreads();
        }
        if (threadIdx.x == 0) atomicAdd(&rowsum[0], red[0]);
    }
}

// ---------------- E: fused /rowsum + einsum + bias2 (r=7 plane provably zero) ----------------
__global__ __launch_bounds__(1024) void k_logits(
    const float* __restrict__ h2raw, const float* __restrict__ rowsum,
    const float* __restrict__ w2, const float* __restrict__ bias2,
    float* __restrict__ out)
{
    __shared__ float w2s[RP * EMB * NCLS];   // 32 KB
    for (int i = threadIdx.x; i < RP * EMB * NCLS; i += 1024) w2s[i] = w2[i];
    __syncthreads();
    int wv = threadIdx.x >> 6, lane = threadIdx.x & 63;
    int n = blockIdx.x * 16 + wv;            // grid=1250 -> n < 20000 exactly
    int c = lane & 15, es = lane >> 4;
    float acc = 0.f;
#pragma unroll
    for (int r = 0; r <= 6; ++r) {
        size_t k = (size_t)r * NN + n;
        float hv = h2raw[k * EMB + lane] / fmaxf(rowsum[k], 1e-6f);
#pragma unroll
        for (int eo = 0; eo < 16; ++eo) {
            float he = __shfl(hv, es * 16 + eo, 64);
            acc = fmaf(he, w2s[(r * EMB + es * 16 + eo) * NCLS + c], acc);
        }
    }
    acc += __shfl_xor(acc, 16, 64);
    acc += __shfl_xor(acc, 32, 64);
    if (lane < 16) out[(size_t)n * NCLS + lane] = acc + bias2[lane];
}

extern "C" void kernel_launch(void* const* d_in, const int* in_sizes, int n_in,
                              void* d_out, int out_size, void* d_ws, size_t ws_size,
                              hipStream_t stream)
{
    const float* rm    = (const float*)d_in[0];
    const int*   hrow  = (const int*)d_in[1];   // sorted source nodes
    const int*   vcol  = (const int*)d_in[4];   // object nodes
    const float* W1    = (const float*)d_in[5];
    const float* b1    = (const float*)d_in[6];
    const float* W2    = (const float*)d_in[7];
    const float* b2    = (const float*)d_in[8];
    const float* w1    = (const float*)d_in[9];
    const float* w2    = (const float*)d_in[10];
    const float* bias1 = (const float*)d_in[11];
    const float* bias2 = (const float*)d_in[12];
    float* out = (float*)d_out;

    float* ws      = (float*)d_ws;
    float* l1      = ws;                    // 2,000,000  [NT][8]
    float* l2      = ws + 2000000;          // 2,000,000  [NT][8]
    float* colsum  = ws + 4000000;          // 160,000 (becomes inverse in-place)
    float* rowsum  = ws + 4160000;          // 160,000
    float* h       = ws + 4320000;          // 1,280,000 (written by k_h)
    float* h2raw   = ws + 5600000;          // 10,240,000
    int*   rowptr  = (int*)(ws + 15840000); // 20,001 ints
    // CSC scratch aliases the h region (dead before k_h writes h)
    int* cnt    = (int*)(ws + 4320000);     // 20,000
    int* cstart = cnt + 20000;              // 20,001
    int* cnt2   = cstart + 20001;           // 20,000
    int* cscidx = cnt2 + 20000;             // 250,000
    // Abuf0/rs0part overlay l1 (dead after k_h)
    float* Abuf0   = ws;                    // 1,280,000
    float* rs0part = ws + 1280000;          // 20,000

    hipMemsetAsync(colsum, 0, (size_t)320000 * sizeof(float), stream);   // colsum+rowsum
    hipMemsetAsync(h2raw, 0, (size_t)SEGMAX * EMB * sizeof(float), stream);
    hipMemsetAsync(cnt, 0, (size_t)20000 * sizeof(int), stream);

    k_rowptr<<<(NN + 256) / 256, 256, 0, stream>>>(hrow, rowptr);
    k_hist  <<<(NT + 255) / 256, 256, 0, stream>>>(vcol, cnt);
    k_scan  <<<1, 1024, 0, stream>>>(cnt, cstart, cnt2);
    k_pos   <<<(NT + 255) / 256, 256, 0, stream>>>(vcol, cnt2, cscidx);
    k_gemv  <<<(NT + 255) / 256, 256, 0, stream>>>(rm, W1, b1, W2, b2, l1, l2);
    k_colsum<<<COLB + REDB, 256, 0, stream>>>(l1, cstart, cscidx, colsum);
    k_inv   <<<(RP * NN + 255) / 256, 256, 0, stream>>>(colsum);
    k_h     <<<(NN * 64) / 256, 256, 0, stream>>>(l1, colsum, rowptr, vcol, w1, bias1, h);
    k_h2    <<<(NN * 64) / 256, 256, 0, stream>>>(l2, rowptr, vcol, h, h2raw, rowsum, Abuf0, rs0part);
    k_red0  <<<65, 256, 0, stream>>>(Abuf0, rs0part, h2raw, rowsum);
    k_logits<<<NN / 16, 1024, 0, stream>>>(h2raw, rowsum, w2, bias2, out);
}